// Round 3
// baseline (2939.565 us; speedup 1.0000x reference)
//
#include <hip/hip_runtime.h>
#include <stdint.h>

typedef unsigned short u16;
typedef short s16x8 __attribute__((ext_vector_type(8)));   // 8 bf16 as raw bits (guide §3 idiom)
typedef float f32x4 __attribute__((ext_vector_type(4)));
typedef unsigned short u16x4 __attribute__((ext_vector_type(4)));
typedef unsigned short u16x8 __attribute__((ext_vector_type(8)));

#define NEX 16384
#define DP1 2048
#define MD 2048
#define RD 10
#define NW (2048u*2048u)   /* 1<<22 */
#define BM 128
#define BN 128
#define BK 32
#define NSTEP 192          /* 3 split-segments * (2048/32) */

__device__ __forceinline__ float bf2f(u16 h) {
  union { unsigned u; float f; } c; c.u = ((unsigned)h) << 16; return c.f;
}
__device__ __forceinline__ u16 f2bf_rne(float f) {
  union { float f; unsigned u; } c; c.f = f;
  unsigned r = ((c.u >> 16) & 1u) + 0x7FFFu;
  return (u16)((c.u + r) >> 16);
}
__device__ __forceinline__ void split2(float v, u16& h, u16& l) {
  h = f2bf_rne(v);
  l = f2bf_rne(v - bf2f(h));
}
__device__ __forceinline__ float adtanh(float v) {
  float av = fabsf(v);
  return av + __logf(1.0f + __expf(-2.0f * av));
}
// global -> LDS direct (16B/lane). LDS dest is wave-uniform base; HW adds lane*16.
__device__ __forceinline__ void gload16(const void* g, void* l) {
  __builtin_amdgcn_global_load_lds(
      (const __attribute__((address_space(1))) void*)g,
      (__attribute__((address_space(3))) void*)l,
      16, 0, 0);
}

// ---------------- weight split: 4 layers of 2048x2048 f32 -> hi/lo bf16 ----------------
__global__ void k_split_w(const float* __restrict__ W0, const float* __restrict__ Wh,
                          u16* __restrict__ wsW) {
  size_t tid = (size_t)blockIdx.x * blockDim.x + threadIdx.x;
  size_t total4 = (4ull * NW) >> 2;
  size_t stride = (size_t)gridDim.x * blockDim.x;
  for (size_t i = tid; i < total4; i += stride) {
    size_t e = i << 2;
    unsigned layer = (unsigned)(e >> 22);
    unsigned rem = (unsigned)(e & (NW - 1));
    const f32x4* src = (layer == 0)
        ? (const f32x4*)(W0 + rem)
        : (const f32x4*)(Wh + (((size_t)(layer - 1)) << 22) + rem);
    f32x4 v = *src;
    u16x4 hv, lv;
#pragma unroll
    for (int e2 = 0; e2 < 4; ++e2) { u16 h, l; split2(v[e2], h, l); hv[e2] = h; lv[e2] = l; }
    *(u16x4*)(wsW + (size_t)(2 * layer) * NW + rem) = hv;
    *(u16x4*)(wsW + (size_t)(2 * layer + 1) * NW + rem) = lv;
  }
}

// ---------- per-row: rowpart = 0.5*||A x||^2 + x.cw + cb ; also split x -> hi/lo ----------
__global__ void k_rows(const float* __restrict__ x, const float* __restrict__ A,
                       const float* __restrict__ cw, const float* __restrict__ cb,
                       float* __restrict__ rowpart, u16* __restrict__ xh, u16* __restrict__ xl,
                       int row0, int nrows) {
  int wave = threadIdx.x >> 6, lane = threadIdx.x & 63;
  int rloc = blockIdx.x * 4 + wave;
  if (rloc >= nrows) return;
  int grow = row0 + rloc;
  const f32x4* xr = (const f32x4*)(x + (size_t)grow * DP1);
  float acc[11];
#pragma unroll
  for (int i = 0; i < 11; ++i) acc[i] = 0.f;
#pragma unroll
  for (int q = 0; q < 8; ++q) {
    int idx = q * 64 + lane;              // f32x4 index within row (0..511)
    f32x4 xv = xr[idx];
#pragma unroll
    for (int r = 0; r < RD; ++r) {
      f32x4 av = ((const f32x4*)(A + (size_t)r * DP1))[idx];
      acc[r] += xv[0]*av[0] + xv[1]*av[1] + xv[2]*av[2] + xv[3]*av[3];
    }
    f32x4 cv = ((const f32x4*)cw)[idx];
    acc[10] += xv[0]*cv[0] + xv[1]*cv[1] + xv[2]*cv[2] + xv[3]*cv[3];
    u16x4 hv, lv;
#pragma unroll
    for (int e = 0; e < 4; ++e) { u16 h, l; split2(xv[e], h, l); hv[e] = h; lv[e] = l; }
    *(u16x4*)(xh + (size_t)rloc * DP1 + (size_t)idx * 4) = hv;
    *(u16x4*)(xl + (size_t)rloc * DP1 + (size_t)idx * 4) = lv;
  }
#pragma unroll
  for (int i = 0; i < 11; ++i)
#pragma unroll
    for (int s = 32; s > 0; s >>= 1) acc[i] += __shfl_xor(acc[i], s, 64);
  if (lane == 0) {
    float quad = 0.f;
#pragma unroll
    for (int r = 0; r < RD; ++r) quad += acc[r] * acc[r];
    rowpart[grow] = 0.5f * quad + acc[10] + cb[0];
  }
}

// ---------------- split-GEMM: C = act(Ah@Bh^T + Ah@Bl^T + Al@Bh^T + bias) ----------------
// A: (nrows x 2048) bf16 pair (chunk-local), B: (2048 x 2048) bf16 pair (row-major, N x K)
// LDS rows are 64B = 4 x 16B slots -> swizzle key is 2 bits: (row&3)<<4, applied
// identically on the staging GLOBAL source and the ds_read address (rule #21 involution).
__global__ __launch_bounds__(256) void k_gemm(
    const u16* __restrict__ Ah, const u16* __restrict__ Al,
    const u16* __restrict__ Bh, const u16* __restrict__ Bl,
    const float* __restrict__ bias,
    const u16* __restrict__ Uph, const u16* __restrict__ Upl,
    u16* __restrict__ Oh, u16* __restrict__ Ol,
    int resmode) {
  __shared__ u16 sA[2][BM * BK];
  __shared__ u16 sB[2][BN * BK];
  int t = threadIdx.x;

  // bijective XCD swizzle (m204): contiguous chunks of the grid per XCD
  unsigned nwg = gridDim.x;
  unsigned bid = blockIdx.x;
  unsigned qq = nwg >> 3, rr8 = nwg & 7;
  unsigned xcd = bid & 7, idx8 = bid >> 3;
  unsigned swz = (xcd < rr8 ? xcd * (qq + 1) : rr8 * (qq + 1) + (xcd - rr8) * qq) + idx8;
  int bm = swz >> 4, bn = swz & 15;
  int rowA0 = bm * BM, rowB0 = bn * BN;

  f32x4 acc[4][4];
#pragma unroll
  for (int m = 0; m < 4; ++m)
#pragma unroll
    for (int n = 0; n < 4; ++n) acc[m][n] = (f32x4)0.f;

  int lane = t & 63, w = t >> 6;
  int wm = w >> 1, wn = w & 1;
  int fr = lane & 15, kb = lane >> 4;

  auto stage = [&](int buf, int step) {
    int seg = step >> 6;
    const u16* Ag = (seg == 2) ? Al : Ah;
    const u16* Bg = (seg == 1) ? Bl : Bh;
    int k0 = (step & 63) * BK;            // element offset in K
    int r = t >> 2;
    int innerb = (t & 3) << 4;            // byte offset within 64B row-slice
#pragma unroll
    for (int q = 0; q < 2; ++q) {
      int rr = q * 64 + r;
      int kbyte = innerb ^ ((rr & 3) << 4);   // inverse swizzle on the GLOBAL side (2-bit key)
      const char* ga = (const char*)(Ag + (size_t)(rowA0 + rr) * DP1 + k0) + kbyte;
      const char* gb = (const char*)(Bg + (size_t)(rowB0 + rr) * DP1 + k0) + kbyte;
      char* la = (char*)(&sA[buf][0]) + q * 4096 + w * 1024;
      char* lb = (char*)(&sB[buf][0]) + q * 4096 + w * 1024;
      gload16(ga, la);
      gload16(gb, lb);
    }
  };

  stage(0, 0);
  __syncthreads();

  int cur = 0;
  for (int s = 0; s < NSTEP; ++s) {
    if (s + 1 < NSTEP) stage(cur ^ 1, s + 1);
    const char* pa = (const char*)&sA[cur][0];
    const char* pb = (const char*)&sB[cur][0];
    s16x8 fa[4], fb[4];
#pragma unroll
    for (int m = 0; m < 4; ++m) {
      int row = wm * 64 + m * 16 + fr;
      fa[m] = *(const s16x8*)(pa + row * 64 + ((kb * 16) ^ ((row & 3) << 4)));
    }
#pragma unroll
    for (int n = 0; n < 4; ++n) {
      int row = wn * 64 + n * 16 + fr;
      fb[n] = *(const s16x8*)(pb + row * 64 + ((kb * 16) ^ ((row & 3) << 4)));
    }
#pragma unroll
    for (int m = 0; m < 4; ++m)
#pragma unroll
      for (int n = 0; n < 4; ++n)
        acc[m][n] = __builtin_amdgcn_mfma_f32_16x16x32_bf16(fa[m], fb[n], acc[m][n], 0, 0, 0);
    __syncthreads();
    cur ^= 1;
  }

  const float H = 1.0f / 3.0f;
#pragma unroll
  for (int m = 0; m < 4; ++m) {
#pragma unroll
    for (int n = 0; n < 4; ++n) {
      int gcol = rowB0 + wn * 64 + n * 16 + fr;     // C/D: col = lane&15
      float bcol = bias[gcol];
#pragma unroll
      for (int j = 0; j < 4; ++j) {
        int grow = rowA0 + wm * 64 + m * 16 + (lane >> 4) * 4 + j;  // row = (lane>>4)*4+reg
        size_t off = (size_t)grow * MD + gcol;
        float v = acc[m][n][j] + bcol;
        float act = adtanh(v);
        float val;
        if (resmode) {
          float up = bf2f(Uph[off]) + bf2f(Upl[off]);
          val = up + H * act;
        } else {
          val = act;
        }
        u16 h, l; split2(val, h, l);
        Oh[off] = h; Ol[off] = l;
      }
    }
  }
}

// ---------------- final: out = u . ww + rowpart ----------------
__global__ void k_final(const u16* __restrict__ Uh, const u16* __restrict__ Ul,
                        const float* __restrict__ ww, const float* __restrict__ rowpart,
                        float* __restrict__ out, int row0, int nrows) {
  int wave = threadIdx.x >> 6, lane = threadIdx.x & 63;
  int rloc = blockIdx.x * 4 + wave;
  if (rloc >= nrows) return;
  int grow = row0 + rloc;
  const u16x8* hr = (const u16x8*)(Uh + (size_t)rloc * MD);
  const u16x8* lr = (const u16x8*)(Ul + (size_t)rloc * MD);
  float acc = 0.f;
#pragma unroll
  for (int q = 0; q < 4; ++q) {
    int idx = q * 64 + lane;              // u16x8 index (0..255)
    u16x8 hv = hr[idx], lv = lr[idx];
    const f32x4* wp = (const f32x4*)(ww + (size_t)idx * 8);
    f32x4 w0 = wp[0], w1 = wp[1];
#pragma unroll
    for (int e = 0; e < 4; ++e) acc += (bf2f(hv[e]) + bf2f(lv[e])) * w0[e];
#pragma unroll
    for (int e = 0; e < 4; ++e) acc += (bf2f(hv[4 + e]) + bf2f(lv[4 + e])) * w1[e];
  }
#pragma unroll
  for (int s = 32; s > 0; s >>= 1) acc += __shfl_xor(acc, s, 64);
  if (lane == 0) out[grow] = acc + rowpart[grow];
}

extern "C" void kernel_launch(void* const* d_in, const int* in_sizes, int n_in,
                              void* d_out, int out_size, void* d_ws, size_t ws_size,
                              hipStream_t stream) {
  const float* x  = (const float*)d_in[0];
  const float* A  = (const float*)d_in[1];
  const float* W0 = (const float*)d_in[2];
  const float* b0 = (const float*)d_in[3];
  const float* Wh = (const float*)d_in[4];
  const float* bh = (const float*)d_in[5];
  const float* ww = (const float*)d_in[6];
  const float* cw = (const float*)d_in[7];
  const float* cb = (const float*)d_in[8];
  float* out = (float*)d_out;

  char* ws = (char*)d_ws;
  u16* wsW = (u16*)ws;                                  // 4*2*NW u16 = 64 MiB
  size_t offRP = 4ull * 2 * NW * 2;                     // 67108864
  float* rowpart = (float*)(ws + offRP);                // 64 KiB
  size_t offSets = offRP + (size_t)NEX * 4;             // 67174400

  int chunkM = 16384;                                   // shrink if ws is small
  while (chunkM > 128 && offSets + 2ull * (size_t)chunkM * 8192 > ws_size) chunkM >>= 1;

  u16* set0 = (u16*)(ws + offSets);
  u16* set1 = (u16*)(ws + offSets + (size_t)chunkM * 8192);
  u16* s0h = set0; u16* s0l = set0 + (size_t)chunkM * 2048;
  u16* s1h = set1; u16* s1l = set1 + (size_t)chunkM * 2048;

  k_split_w<<<2048, 256, 0, stream>>>(W0, Wh, wsW);

  for (int row0 = 0; row0 < NEX; row0 += chunkM) {
    int nrows = NEX - row0 < chunkM ? NEX - row0 : chunkM;
    int gblocks = (nrows / BM) * (MD / BN);
    int rblocks = (nrows + 3) / 4;
    k_rows<<<rblocks, 256, 0, stream>>>(x, A, cw, cb, rowpart, s0h, s0l, row0, nrows);
    // layer 0: set0 -> set1 (no residual)
    k_gemm<<<gblocks, 256, 0, stream>>>(s0h, s0l, wsW + 0ull*NW, wsW + 1ull*NW, b0,
                                        nullptr, nullptr, s1h, s1l, 0);
    // layer 1: set1 -> set0 (residual from set1)
    k_gemm<<<gblocks, 256, 0, stream>>>(s1h, s1l, wsW + 2ull*NW, wsW + 3ull*NW, bh + 0*MD,
                                        s1h, s1l, s0h, s0l, 1);
    // layer 2: set0 -> set1
    k_gemm<<<gblocks, 256, 0, stream>>>(s0h, s0l, wsW + 4ull*NW, wsW + 5ull*NW, bh + 1*MD,
                                        s0h, s0l, s1h, s1l, 1);
    // layer 3: set1 -> set0
    k_gemm<<<gblocks, 256, 0, stream>>>(s1h, s1l, wsW + 6ull*NW, wsW + 7ull*NW, bh + 2*MD,
                                        s1h, s1l, s0h, s0l, 1);
    k_final<<<rblocks, 256, 0, stream>>>(s0h, s0l, ww, rowpart, out, row0, nrows);
  }
}

// Round 5
// 2848.131 us; speedup vs baseline: 1.0321x; 1.0321x over previous
//
#include <hip/hip_runtime.h>
#include <stdint.h>

typedef unsigned short u16;
typedef short s16x8 __attribute__((ext_vector_type(8)));   // 8 bf16 as raw bits (guide §3 idiom)
typedef float f32x4 __attribute__((ext_vector_type(4)));
typedef unsigned short u16x4 __attribute__((ext_vector_type(4)));
typedef unsigned short u16x8 __attribute__((ext_vector_type(8)));

#define NEX 16384
#define DP1 2048
#define MD 2048
#define RD 10
#define NW (2048u*2048u)   /* 1<<22 */
#define BM 128
#define BN 128
#define BK 32
#define NSTEP 192          /* 3 split-segments * (2048/32) */

__device__ __forceinline__ float bf2f(u16 h) {
  union { unsigned u; float f; } c; c.u = ((unsigned)h) << 16; return c.f;
}
__device__ __forceinline__ u16 f2bf_rne(float f) {
  union { float f; unsigned u; } c; c.f = f;
  unsigned r = ((c.u >> 16) & 1u) + 0x7FFFu;
  return (u16)((c.u + r) >> 16);
}
__device__ __forceinline__ void split2(float v, u16& h, u16& l) {
  h = f2bf_rne(v);
  l = f2bf_rne(v - bf2f(h));
}
__device__ __forceinline__ float adtanh(float v) {
  float av = fabsf(v);
  return av + __logf(1.0f + __expf(-2.0f * av));
}
// global -> LDS direct (16B/lane). LDS dest is wave-uniform base; HW adds lane*16.
__device__ __forceinline__ void gload16(const void* g, void* l) {
  __builtin_amdgcn_global_load_lds(
      (const __attribute__((address_space(1))) void*)g,
      (__attribute__((address_space(3))) void*)l,
      16, 0, 0);
}

// ---------------- weight split: 4 layers of 2048x2048 f32 -> hi/lo bf16 ----------------
__global__ void k_split_w(const float* __restrict__ W0, const float* __restrict__ Wh,
                          u16* __restrict__ wsW) {
  size_t tid = (size_t)blockIdx.x * blockDim.x + threadIdx.x;
  size_t total4 = (4ull * NW) >> 2;
  size_t stride = (size_t)gridDim.x * blockDim.x;
  for (size_t i = tid; i < total4; i += stride) {
    size_t e = i << 2;
    unsigned layer = (unsigned)(e >> 22);
    unsigned rem = (unsigned)(e & (NW - 1));
    const f32x4* src = (layer == 0)
        ? (const f32x4*)(W0 + rem)
        : (const f32x4*)(Wh + (((size_t)(layer - 1)) << 22) + rem);
    f32x4 v = *src;
    u16x4 hv, lv;
#pragma unroll
    for (int e2 = 0; e2 < 4; ++e2) { u16 h, l; split2(v[e2], h, l); hv[e2] = h; lv[e2] = l; }
    *(u16x4*)(wsW + (size_t)(2 * layer) * NW + rem) = hv;
    *(u16x4*)(wsW + (size_t)(2 * layer + 1) * NW + rem) = lv;
  }
}

// ---------- per-row: rowpart = 0.5*||A x||^2 + x.cw + cb ; also split x -> hi/lo ----------
__global__ void k_rows(const float* __restrict__ x, const float* __restrict__ A,
                       const float* __restrict__ cw, const float* __restrict__ cb,
                       float* __restrict__ rowpart, u16* __restrict__ xh, u16* __restrict__ xl,
                       int row0, int nrows) {
  int wave = threadIdx.x >> 6, lane = threadIdx.x & 63;
  int rloc = blockIdx.x * 4 + wave;
  if (rloc >= nrows) return;
  int grow = row0 + rloc;
  const f32x4* xr = (const f32x4*)(x + (size_t)grow * DP1);
  float acc[11];
#pragma unroll
  for (int i = 0; i < 11; ++i) acc[i] = 0.f;
#pragma unroll
  for (int q = 0; q < 8; ++q) {
    int idx = q * 64 + lane;              // f32x4 index within row (0..511)
    f32x4 xv = xr[idx];
#pragma unroll
    for (int r = 0; r < RD; ++r) {
      f32x4 av = ((const f32x4*)(A + (size_t)r * DP1))[idx];
      acc[r] += xv[0]*av[0] + xv[1]*av[1] + xv[2]*av[2] + xv[3]*av[3];
    }
    f32x4 cv = ((const f32x4*)cw)[idx];
    acc[10] += xv[0]*cv[0] + xv[1]*cv[1] + xv[2]*cv[2] + xv[3]*cv[3];
    u16x4 hv, lv;
#pragma unroll
    for (int e = 0; e < 4; ++e) { u16 h, l; split2(xv[e], h, l); hv[e] = h; lv[e] = l; }
    *(u16x4*)(xh + (size_t)rloc * DP1 + (size_t)idx * 4) = hv;
    *(u16x4*)(xl + (size_t)rloc * DP1 + (size_t)idx * 4) = lv;
  }
#pragma unroll
  for (int i = 0; i < 11; ++i)
#pragma unroll
    for (int s = 32; s > 0; s >>= 1) acc[i] += __shfl_xor(acc[i], s, 64);
  if (lane == 0) {
    float quad = 0.f;
#pragma unroll
    for (int r = 0; r < RD; ++r) quad += acc[r] * acc[r];
    rowpart[grow] = 0.5f * quad + acc[10] + cb[0];
  }
}

// ---------------- split-GEMM: C = act(Ah@Bh^T + Ah@Bl^T + Al@Bh^T + bias) ----------------
// A: (nrows x 2048) bf16 pair (chunk-local), B: (2048 x 2048) bf16 pair (row-major, N x K)
// LDS rows are 64B = 4 x 16B slots. Bank group of (row,slot) = (4*row+slot) mod 8, so the
// swizzle key must be (row>>1)&3 (row&3 left fr and fr+4 on the same banks -> 4-way, the
// 5e7 SQ_LDS_BANK_CONFLICT seen in round 3). Key applied identically on the staging
// GLOBAL source and the ds_read address (rule #21 involution).
__global__ __launch_bounds__(256) void k_gemm(
    const u16* __restrict__ Ah, const u16* __restrict__ Al,
    const u16* __restrict__ Bh, const u16* __restrict__ Bl,
    const float* __restrict__ bias,
    const u16* __restrict__ Uph, const u16* __restrict__ Upl,
    u16* __restrict__ Oh, u16* __restrict__ Ol,
    int resmode) {
  __shared__ u16 sA[2][BM * BK];
  __shared__ u16 sB[2][BN * BK];
  int t = threadIdx.x;

  // bijective XCD swizzle (m204): contiguous chunks of the grid per XCD
  unsigned nwg = gridDim.x;
  unsigned bid = blockIdx.x;
  unsigned qq = nwg >> 3, rr8 = nwg & 7;
  unsigned xcd = bid & 7, idx8 = bid >> 3;
  unsigned swz = (xcd < rr8 ? xcd * (qq + 1) : rr8 * (qq + 1) + (xcd - rr8) * qq) + idx8;
  int bm = swz >> 4, bn = swz & 15;
  int rowA0 = bm * BM, rowB0 = bn * BN;

  f32x4 acc[4][4];
#pragma unroll
  for (int m = 0; m < 4; ++m)
#pragma unroll
    for (int n = 0; n < 4; ++n) acc[m][n] = (f32x4)0.f;

  int lane = t & 63, w = t >> 6;
  int wm = w >> 1, wn = w & 1;
  int fr = lane & 15, kb = lane >> 4;

  auto stage = [&](int buf, int step) {
    int seg = step >> 6;
    const u16* Ag = (seg == 2) ? Al : Ah;
    const u16* Bg = (seg == 1) ? Bl : Bh;
    int k0 = (step & 63) * BK;            // element offset in K
    int r = t >> 2;
    int innerb = (t & 3) << 4;            // byte offset within 64B row-slice
#pragma unroll
    for (int q = 0; q < 2; ++q) {
      int rr = q * 64 + r;
      int kbyte = innerb ^ (((rr >> 1) & 3) << 4);  // inverse swizzle on the GLOBAL side
      const char* ga = (const char*)(Ag + (size_t)(rowA0 + rr) * DP1 + k0) + kbyte;
      const char* gb = (const char*)(Bg + (size_t)(rowB0 + rr) * DP1 + k0) + kbyte;
      char* la = (char*)(&sA[buf][0]) + q * 4096 + w * 1024;
      char* lb = (char*)(&sB[buf][0]) + q * 4096 + w * 1024;
      gload16(ga, la);
      gload16(gb, lb);
    }
  };

  stage(0, 0);
  __syncthreads();

  int cur = 0;
  for (int s = 0; s < NSTEP; ++s) {
    if (s + 1 < NSTEP) stage(cur ^ 1, s + 1);
    const char* pa = (const char*)&sA[cur][0];
    const char* pb = (const char*)&sB[cur][0];
    s16x8 fa[4], fb[4];
#pragma unroll
    for (int m = 0; m < 4; ++m) {
      int row = wm * 64 + m * 16 + fr;
      fa[m] = *(const s16x8*)(pa + row * 64 + ((kb * 16) ^ (((row >> 1) & 3) << 4)));
    }
#pragma unroll
    for (int n = 0; n < 4; ++n) {
      int row = wn * 64 + n * 16 + fr;
      fb[n] = *(const s16x8*)(pb + row * 64 + ((kb * 16) ^ (((row >> 1) & 3) << 4)));
    }
#pragma unroll
    for (int m = 0; m < 4; ++m)
#pragma unroll
      for (int n = 0; n < 4; ++n)
        acc[m][n] = __builtin_amdgcn_mfma_f32_16x16x32_bf16(fa[m], fb[n], acc[m][n], 0, 0, 0);
    __syncthreads();
    cur ^= 1;
  }

  const float H = 1.0f / 3.0f;
#pragma unroll
  for (int m = 0; m < 4; ++m) {
#pragma unroll
    for (int n = 0; n < 4; ++n) {
      int gcol = rowB0 + wn * 64 + n * 16 + fr;     // C/D: col = lane&15
      float bcol = bias[gcol];
#pragma unroll
      for (int j = 0; j < 4; ++j) {
        int grow = rowA0 + wm * 64 + m * 16 + (lane >> 4) * 4 + j;  // row = (lane>>4)*4+reg
        size_t off = (size_t)grow * MD + gcol;
        float v = acc[m][n][j] + bcol;
        float act = adtanh(v);
        float val;
        if (resmode) {
          float up = bf2f(Uph[off]) + bf2f(Upl[off]);
          val = up + H * act;
        } else {
          val = act;
        }
        u16 h, l; split2(val, h, l);
        Oh[off] = h; Ol[off] = l;
      }
    }
  }
}

// ---------------- final: out = u . ww + rowpart ----------------
__global__ void k_final(const u16* __restrict__ Uh, const u16* __restrict__ Ul,
                        const float* __restrict__ ww, const float* __restrict__ rowpart,
                        float* __restrict__ out, int row0, int nrows) {
  int wave = threadIdx.x >> 6, lane = threadIdx.x & 63;
  int rloc = blockIdx.x * 4 + wave;
  if (rloc >= nrows) return;
  int grow = row0 + rloc;
  const u16x8* hr = (const u16x8*)(Uh + (size_t)rloc * MD);
  const u16x8* lr = (const u16x8*)(Ul + (size_t)rloc * MD);
  float acc = 0.f;
#pragma unroll
  for (int q = 0; q < 4; ++q) {
    int idx = q * 64 + lane;              // u16x8 index (0..255)
    u16x8 hv = hr[idx], lv = lr[idx];
    const f32x4* wp = (const f32x4*)(ww + (size_t)idx * 8);
    f32x4 w0 = wp[0], w1 = wp[1];
#pragma unroll
    for (int e = 0; e < 4; ++e) acc += (bf2f(hv[e]) + bf2f(lv[e])) * w0[e];
#pragma unroll
    for (int e = 0; e < 4; ++e) acc += (bf2f(hv[4 + e]) + bf2f(lv[4 + e])) * w1[e];
  }
#pragma unroll
  for (int s = 32; s > 0; s >>= 1) acc += __shfl_xor(acc, s, 64);
  if (lane == 0) out[grow] = acc + rowpart[grow];
}

extern "C" void kernel_launch(void* const* d_in, const int* in_sizes, int n_in,
                              void* d_out, int out_size, void* d_ws, size_t ws_size,
                              hipStream_t stream) {
  const float* x  = (const float*)d_in[0];
  const float* A  = (const float*)d_in[1];
  const float* W0 = (const float*)d_in[2];
  const float* b0 = (const float*)d_in[3];
  const float* Wh = (const float*)d_in[4];
  const float* bh = (const float*)d_in[5];
  const float* ww = (const float*)d_in[6];
  const float* cw = (const float*)d_in[7];
  const float* cb = (const float*)d_in[8];
  float* out = (float*)d_out;

  char* ws = (char*)d_ws;
  u16* wsW = (u16*)ws;                                  // 4*2*NW u16 = 64 MiB
  size_t offRP = 4ull * 2 * NW * 2;                     // 67108864
  float* rowpart = (float*)(ws + offRP);                // 64 KiB
  size_t offSets = offRP + (size_t)NEX * 4;             // 67174400

  int chunkM = 16384;                                   // shrink if ws is small
  while (chunkM > 128 && offSets + 2ull * (size_t)chunkM * 8192 > ws_size) chunkM >>= 1;

  u16* set0 = (u16*)(ws + offSets);
  u16* set1 = (u16*)(ws + offSets + (size_t)chunkM * 8192);
  u16* s0h = set0; u16* s0l = set0 + (size_t)chunkM * 2048;
  u16* s1h = set1; u16* s1l = set1 + (size_t)chunkM * 2048;

  k_split_w<<<2048, 256, 0, stream>>>(W0, Wh, wsW);

  for (int row0 = 0; row0 < NEX; row0 += chunkM) {
    int nrows = NEX - row0 < chunkM ? NEX - row0 : chunkM;
    int gblocks = (nrows / BM) * (MD / BN);
    int rblocks = (nrows + 3) / 4;
    k_rows<<<rblocks, 256, 0, stream>>>(x, A, cw, cb, rowpart, s0h, s0l, row0, nrows);
    // layer 0: set0 -> set1 (no residual)
    k_gemm<<<gblocks, 256, 0, stream>>>(s0h, s0l, wsW + 0ull*NW, wsW + 1ull*NW, b0,
                                        nullptr, nullptr, s1h, s1l, 0);
    // layer 1: set1 -> set0 (residual from set1)
    k_gemm<<<gblocks, 256, 0, stream>>>(s1h, s1l, wsW + 2ull*NW, wsW + 3ull*NW, bh + 0*MD,
                                        s1h, s1l, s0h, s0l, 1);
    // layer 2: set0 -> set1
    k_gemm<<<gblocks, 256, 0, stream>>>(s0h, s0l, wsW + 4ull*NW, wsW + 5ull*NW, bh + 1*MD,
                                        s0h, s0l, s1h, s1l, 1);
    // layer 3: set1 -> set0
    k_gemm<<<gblocks, 256, 0, stream>>>(s1h, s1l, wsW + 6ull*NW, wsW + 7ull*NW, bh + 2*MD,
                                        s1h, s1l, s0h, s0l, 1);
    k_final<<<rblocks, 256, 0, stream>>>(s0h, s0l, ww, rowpart, out, row0, nrows);
  }
}

// Round 6
// 1666.846 us; speedup vs baseline: 1.7635x; 1.7087x over previous
//
#include <hip/hip_runtime.h>
#include <stdint.h>

typedef unsigned short u16;
typedef _Float16 f16;
typedef _Float16 f16x4 __attribute__((ext_vector_type(4)));
typedef _Float16 f16x8 __attribute__((ext_vector_type(8)));
typedef float f32x4 __attribute__((ext_vector_type(4)));

#define NEX 16384
#define DP1 2048
#define MD 2048
#define RD 10
#define NW (2048u*2048u)   /* 1<<22 */
#define BM 128
#define BN 128
#define BK 32
#define NSTEP 64           /* 2048/32; both W segments consumed per step */

__device__ __forceinline__ float adtanh(float v) {
  float av = fabsf(v);
  return av + __logf(1.0f + __expf(-2.0f * av));
}
// global -> LDS direct (16B/lane). LDS dest is wave-uniform base; HW adds lane*16.
__device__ __forceinline__ void gload16(const void* g, void* l) {
  __builtin_amdgcn_global_load_lds(
      (const __attribute__((address_space(1))) void*)g,
      (__attribute__((address_space(3))) void*)l,
      16, 0, 0);
}

// ---------------- weight split: 4 layers of 2048x2048 f32 -> fp16 hi/lo pair ----------------
__global__ void k_split_w(const float* __restrict__ W0, const float* __restrict__ Wh,
                          f16* __restrict__ wsW) {
  size_t tid = (size_t)blockIdx.x * blockDim.x + threadIdx.x;
  size_t total4 = (4ull * NW) >> 2;
  size_t stride = (size_t)gridDim.x * blockDim.x;
  for (size_t i = tid; i < total4; i += stride) {
    size_t e = i << 2;
    unsigned layer = (unsigned)(e >> 22);
    unsigned rem = (unsigned)(e & (NW - 1));
    const f32x4* src = (layer == 0)
        ? (const f32x4*)(W0 + rem)
        : (const f32x4*)(Wh + (((size_t)(layer - 1)) << 22) + rem);
    f32x4 v = *src;
    f16x4 hv, lv;
#pragma unroll
    for (int e2 = 0; e2 < 4; ++e2) {
      f16 h = (f16)v[e2];
      hv[e2] = h;
      lv[e2] = (f16)(v[e2] - (float)h);
    }
    *(f16x4*)(wsW + (size_t)(2 * layer) * NW + rem) = hv;
    *(f16x4*)(wsW + (size_t)(2 * layer + 1) * NW + rem) = lv;
  }
}

// ---------- per-row: rowpart = 0.5*||A x||^2 + x.cw + cb ; also cast x -> fp16 ----------
__global__ void k_rows(const float* __restrict__ x, const float* __restrict__ A,
                       const float* __restrict__ cw, const float* __restrict__ cb,
                       float* __restrict__ rowpart, f16* __restrict__ xh,
                       int row0, int nrows) {
  int wave = threadIdx.x >> 6, lane = threadIdx.x & 63;
  int rloc = blockIdx.x * 4 + wave;
  if (rloc >= nrows) return;
  int grow = row0 + rloc;
  const f32x4* xr = (const f32x4*)(x + (size_t)grow * DP1);
  float acc[11];
#pragma unroll
  for (int i = 0; i < 11; ++i) acc[i] = 0.f;
#pragma unroll
  for (int q = 0; q < 8; ++q) {
    int idx = q * 64 + lane;              // f32x4 index within row (0..511)
    f32x4 xv = xr[idx];
#pragma unroll
    for (int r = 0; r < RD; ++r) {
      f32x4 av = ((const f32x4*)(A + (size_t)r * DP1))[idx];
      acc[r] += xv[0]*av[0] + xv[1]*av[1] + xv[2]*av[2] + xv[3]*av[3];
    }
    f32x4 cv = ((const f32x4*)cw)[idx];
    acc[10] += xv[0]*cv[0] + xv[1]*cv[1] + xv[2]*cv[2] + xv[3]*cv[3];
    f16x4 hv;
#pragma unroll
    for (int e = 0; e < 4; ++e) hv[e] = (f16)xv[e];
    *(f16x4*)(xh + (size_t)rloc * DP1 + (size_t)idx * 4) = hv;
  }
#pragma unroll
  for (int i = 0; i < 11; ++i)
#pragma unroll
    for (int s = 32; s > 0; s >>= 1) acc[i] += __shfl_xor(acc[i], s, 64);
  if (lane == 0) {
    float quad = 0.f;
#pragma unroll
    for (int r = 0; r < RD; ++r) quad += acc[r] * acc[r];
    rowpart[grow] = 0.5f * quad + acc[10] + cb[0];
  }
}

// ------------- split-GEMM: C = act(A@Bh^T + A@Bl^T + bias), A single fp16 -------------
// A: (nrows x 2048) fp16 (chunk-local), B: (2048 x 2048) fp16 pair (row-major, N x K)
// Per K-step: stage A-tile + BOTH B tiles, 32 MFMA between one barrier pair.
// LDS rows are 64B = 4 x 16B slots; swizzle key (row>>1)&3 on both sides of the
// staging/read involution (round-5 verified: SQ_LDS_BANK_CONFLICT = 0).
__global__ __launch_bounds__(256) void k_gemm(
    const f16* __restrict__ Ah,
    const f16* __restrict__ Bh, const f16* __restrict__ Bl,
    const float* __restrict__ bias,
    const f16* __restrict__ Up, f16* __restrict__ O,
    int resmode) {
  __shared__ f16 sA[2][BM * BK];
  __shared__ f16 sB[2][2][BN * BK];   // [buf][hi/lo][tile]
  int t = threadIdx.x;

  // bijective XCD swizzle (m204): contiguous chunks of the grid per XCD
  unsigned nwg = gridDim.x;
  unsigned bid = blockIdx.x;
  unsigned qq = nwg >> 3, rr8 = nwg & 7;
  unsigned xcd = bid & 7, idx8 = bid >> 3;
  unsigned swz = (xcd < rr8 ? xcd * (qq + 1) : rr8 * (qq + 1) + (xcd - rr8) * qq) + idx8;
  int bm = swz >> 4, bn = swz & 15;
  int rowA0 = bm * BM, rowB0 = bn * BN;

  f32x4 acc[4][4];
#pragma unroll
  for (int m = 0; m < 4; ++m)
#pragma unroll
    for (int n = 0; n < 4; ++n) acc[m][n] = (f32x4)0.f;

  int lane = t & 63, w = t >> 6;
  int wm = w >> 1, wn = w & 1;
  int fr = lane & 15, kb = lane >> 4;

  auto stage = [&](int buf, int s) {
    int k0 = s * BK;                      // element offset in K
    int r = t >> 2;                       // 0..63
    int innerb = (t & 3) << 4;            // byte offset within 64B row-slice
#pragma unroll
    for (int q = 0; q < 2; ++q) {
      int rr = q * 64 + r;
      int kbyte = innerb ^ (((rr >> 1) & 3) << 4);  // inverse swizzle on the GLOBAL side
      const char* ga  = (const char*)(Ah + (size_t)(rowA0 + rr) * DP1 + k0) + kbyte;
      const char* gbh = (const char*)(Bh + (size_t)(rowB0 + rr) * DP1 + k0) + kbyte;
      const char* gbl = (const char*)(Bl + (size_t)(rowB0 + rr) * DP1 + k0) + kbyte;
      char* la  = (char*)(&sA[buf][0])    + q * 4096 + w * 1024;
      char* lbh = (char*)(&sB[buf][0][0]) + q * 4096 + w * 1024;
      char* lbl = (char*)(&sB[buf][1][0]) + q * 4096 + w * 1024;
      gload16(ga,  la);
      gload16(gbh, lbh);
      gload16(gbl, lbl);
    }
  };

  stage(0, 0);
  __syncthreads();

  int cur = 0;
  for (int s = 0; s < NSTEP; ++s) {
    if (s + 1 < NSTEP) stage(cur ^ 1, s + 1);
    const char* pa  = (const char*)&sA[cur][0];
    const char* pbh = (const char*)&sB[cur][0][0];
    const char* pbl = (const char*)&sB[cur][1][0];
    f16x8 fa[4], fbh[4], fbl[4];
#pragma unroll
    for (int m = 0; m < 4; ++m) {
      int row = wm * 64 + m * 16 + fr;
      int off = row * 64 + ((kb * 16) ^ (((row >> 1) & 3) << 4));
      fa[m] = *(const f16x8*)(pa + off);
    }
#pragma unroll
    for (int n = 0; n < 4; ++n) {
      int row = wn * 64 + n * 16 + fr;
      int off = row * 64 + ((kb * 16) ^ (((row >> 1) & 3) << 4));
      fbh[n] = *(const f16x8*)(pbh + off);
      fbl[n] = *(const f16x8*)(pbl + off);
    }
#pragma unroll
    for (int m = 0; m < 4; ++m)
#pragma unroll
      for (int n = 0; n < 4; ++n)
        acc[m][n] = __builtin_amdgcn_mfma_f32_16x16x32_f16(fa[m], fbh[n], acc[m][n], 0, 0, 0);
#pragma unroll
    for (int m = 0; m < 4; ++m)
#pragma unroll
      for (int n = 0; n < 4; ++n)
        acc[m][n] = __builtin_amdgcn_mfma_f32_16x16x32_f16(fa[m], fbl[n], acc[m][n], 0, 0, 0);
    __syncthreads();
    cur ^= 1;
  }

  const float H = 1.0f / 3.0f;
#pragma unroll
  for (int m = 0; m < 4; ++m) {
#pragma unroll
    for (int n = 0; n < 4; ++n) {
      int gcol = rowB0 + wn * 64 + n * 16 + fr;     // C/D: col = lane&15
      float bcol = bias[gcol];
#pragma unroll
      for (int j = 0; j < 4; ++j) {
        int grow = rowA0 + wm * 64 + m * 16 + (lane >> 4) * 4 + j;  // row = (lane>>4)*4+reg
        size_t off = (size_t)grow * MD + gcol;
        float v = acc[m][n][j] + bcol;
        float act = adtanh(v);
        float val;
        if (resmode) {
          val = (float)Up[off] + H * act;
        } else {
          val = act;
        }
        O[off] = (f16)val;
      }
    }
  }
}

// ---------------- final: out = u . ww + rowpart ----------------
__global__ void k_final(const f16* __restrict__ U,
                        const float* __restrict__ ww, const float* __restrict__ rowpart,
                        float* __restrict__ out, int row0, int nrows) {
  int wave = threadIdx.x >> 6, lane = threadIdx.x & 63;
  int rloc = blockIdx.x * 4 + wave;
  if (rloc >= nrows) return;
  int grow = row0 + rloc;
  const f16x8* ur = (const f16x8*)(U + (size_t)rloc * MD);
  float acc = 0.f;
#pragma unroll
  for (int q = 0; q < 4; ++q) {
    int idx = q * 64 + lane;              // f16x8 index (0..255)
    f16x8 uv = ur[idx];
    const f32x4* wp = (const f32x4*)(ww + (size_t)idx * 8);
    f32x4 w0 = wp[0], w1 = wp[1];
#pragma unroll
    for (int e = 0; e < 4; ++e) acc += (float)uv[e] * w0[e];
#pragma unroll
    for (int e = 0; e < 4; ++e) acc += (float)uv[4 + e] * w1[e];
  }
#pragma unroll
  for (int s = 32; s > 0; s >>= 1) acc += __shfl_xor(acc, s, 64);
  if (lane == 0) out[grow] = acc + rowpart[grow];
}

extern "C" void kernel_launch(void* const* d_in, const int* in_sizes, int n_in,
                              void* d_out, int out_size, void* d_ws, size_t ws_size,
                              hipStream_t stream) {
  const float* x  = (const float*)d_in[0];
  const float* A  = (const float*)d_in[1];
  const float* W0 = (const float*)d_in[2];
  const float* b0 = (const float*)d_in[3];
  const float* Wh = (const float*)d_in[4];
  const float* bh = (const float*)d_in[5];
  const float* ww = (const float*)d_in[6];
  const float* cw = (const float*)d_in[7];
  const float* cb = (const float*)d_in[8];
  float* out = (float*)d_out;

  char* ws = (char*)d_ws;
  f16* wsW = (f16*)ws;                                  // 4*2*NW f16 = 64 MiB
  size_t offRP = 4ull * 2 * NW * 2;                     // 67108864
  float* rowpart = (float*)(ws + offRP);                // 64 KiB
  size_t offSets = offRP + (size_t)NEX * 4;             // 67174400

  int chunkM = 16384;                                   // shrink if ws is small
  while (chunkM > 128 && offSets + 2ull * (size_t)chunkM * 4096 > ws_size) chunkM >>= 1;

  f16* s0 = (f16*)(ws + offSets);
  f16* s1 = (f16*)(ws + offSets + (size_t)chunkM * 4096);

  k_split_w<<<2048, 256, 0, stream>>>(W0, Wh, wsW);

  for (int row0 = 0; row0 < NEX; row0 += chunkM) {
    int nrows = NEX - row0 < chunkM ? NEX - row0 : chunkM;
    int gblocks = (nrows / BM) * (MD / BN);
    int rblocks = (nrows + 3) / 4;
    k_rows<<<rblocks, 256, 0, stream>>>(x, A, cw, cb, rowpart, s0, row0, nrows);
    // layer 0: s0 -> s1 (no residual)
    k_gemm<<<gblocks, 256, 0, stream>>>(s0, wsW + 0ull*NW, wsW + 1ull*NW, b0,
                                        nullptr, s1, 0);
    // layer 1: s1 -> s0 (residual from s1)
    k_gemm<<<gblocks, 256, 0, stream>>>(s1, wsW + 2ull*NW, wsW + 3ull*NW, bh + 0*MD,
                                        s1, s0, 1);
    // layer 2: s0 -> s1
    k_gemm<<<gblocks, 256, 0, stream>>>(s0, wsW + 4ull*NW, wsW + 5ull*NW, bh + 1*MD,
                                        s0, s1, 1);
    // layer 3: s1 -> s0
    k_gemm<<<gblocks, 256, 0, stream>>>(s1, wsW + 6ull*NW, wsW + 7ull*NW, bh + 2*MD,
                                        s1, s0, 1);
    k_final<<<rblocks, 256, 0, stream>>>(s0, ww, rowpart, out, row0, nrows);
  }
}

// Round 7
// 1502.300 us; speedup vs baseline: 1.9567x; 1.1095x over previous
//
#include <hip/hip_runtime.h>
#include <stdint.h>

typedef _Float16 f16;
typedef _Float16 f16x4 __attribute__((ext_vector_type(4)));
typedef _Float16 f16x8 __attribute__((ext_vector_type(8)));
typedef float f32x4 __attribute__((ext_vector_type(4)));

#define NEX 16384
#define DP1 2048
#define MD 2048
#define RD 10
#define NW (2048u*2048u)   /* 1<<22 */
#define BM 256
#define BN 256
#define BK 32
#define KTILES 128         /* K_ext = 4096 (A@Bh then A@Bl) / BK */

__device__ __forceinline__ float adtanh(float v) {
  float av = fabsf(v);
  return av + __logf(1.0f + __expf(-2.0f * av));
}
// global -> LDS direct (16B/lane). LDS dest is wave-uniform base; HW adds lane*16.
__device__ __forceinline__ void gload16(const void* g, void* l) {
  __builtin_amdgcn_global_load_lds(
      (const __attribute__((address_space(1))) void*)g,
      (__attribute__((address_space(3))) void*)l,
      16, 0, 0);
}

// ---------------- weight split: 4 layers of 2048x2048 f32 -> fp16 hi/lo pair ----------------
__global__ void k_split_w(const float* __restrict__ W0, const float* __restrict__ Wh,
                          f16* __restrict__ wsW) {
  size_t tid = (size_t)blockIdx.x * blockDim.x + threadIdx.x;
  size_t total4 = (4ull * NW) >> 2;
  size_t stride = (size_t)gridDim.x * blockDim.x;
  for (size_t i = tid; i < total4; i += stride) {
    size_t e = i << 2;
    unsigned layer = (unsigned)(e >> 22);
    unsigned rem = (unsigned)(e & (NW - 1));
    const f32x4* src = (layer == 0)
        ? (const f32x4*)(W0 + rem)
        : (const f32x4*)(Wh + (((size_t)(layer - 1)) << 22) + rem);
    f32x4 v = *src;
    f16x4 hv, lv;
#pragma unroll
    for (int e2 = 0; e2 < 4; ++e2) {
      f16 h = (f16)v[e2];
      hv[e2] = h;
      lv[e2] = (f16)(v[e2] - (float)h);
    }
    *(f16x4*)(wsW + (size_t)(2 * layer) * NW + rem) = hv;
    *(f16x4*)(wsW + (size_t)(2 * layer + 1) * NW + rem) = lv;
  }
}

// ---------- per-row: rowpart = 0.5*||A x||^2 + x.cw + cb ; also cast x -> fp16 ----------
__global__ void k_rows(const float* __restrict__ x, const float* __restrict__ A,
                       const float* __restrict__ cw, const float* __restrict__ cb,
                       float* __restrict__ rowpart, f16* __restrict__ xh,
                       int row0, int nrows) {
  int wave = threadIdx.x >> 6, lane = threadIdx.x & 63;
  int rloc = blockIdx.x * 4 + wave;
  if (rloc >= nrows) return;
  int grow = row0 + rloc;
  const f32x4* xr = (const f32x4*)(x + (size_t)grow * DP1);
  float acc[11];
#pragma unroll
  for (int i = 0; i < 11; ++i) acc[i] = 0.f;
#pragma unroll
  for (int q = 0; q < 8; ++q) {
    int idx = q * 64 + lane;              // f32x4 index within row (0..511)
    f32x4 xv = xr[idx];
#pragma unroll
    for (int r = 0; r < RD; ++r) {
      f32x4 av = ((const f32x4*)(A + (size_t)r * DP1))[idx];
      acc[r] += xv[0]*av[0] + xv[1]*av[1] + xv[2]*av[2] + xv[3]*av[3];
    }
    f32x4 cv = ((const f32x4*)cw)[idx];
    acc[10] += xv[0]*cv[0] + xv[1]*cv[1] + xv[2]*cv[2] + xv[3]*cv[3];
    f16x4 hv;
#pragma unroll
    for (int e = 0; e < 4; ++e) hv[e] = (f16)xv[e];
    *(f16x4*)(xh + (size_t)rloc * DP1 + (size_t)idx * 4) = hv;
  }
#pragma unroll
  for (int i = 0; i < 11; ++i)
#pragma unroll
    for (int s = 32; s > 0; s >>= 1) acc[i] += __shfl_xor(acc[i], s, 64);
  if (lane == 0) {
    float quad = 0.f;
#pragma unroll
    for (int r = 0; r < RD; ++r) quad += acc[r] * acc[r];
    rowpart[grow] = 0.5f * quad + acc[10] + cb[0];
  }
}

// ------------- 256^2 deep-pipelined split-GEMM: C = act(A@Bh^T + A@Bl^T + bias) -------------
// K-extension: standard GEMM over K_ext=4096, B_ext=[Bh;Bl], A repeated (k0=(kt&63)*BK).
// 4-slot LDS ring (128 KiB dynamic), stage kt+2 while computing kt; counted
// s_waitcnt vmcnt(4) at K-tile boundary (never drains to 0 mid-loop). 8 waves (2Mx4N),
// 128x64 out/wave, two 16-MFMA clusters per K-tile with s_setprio. Swizzle key
// (row>>1)&3 on both staging-source and ds_read (round-5 verified: 0 conflicts).
__global__ __launch_bounds__(512, 2) void k_gemm(
    const f16* __restrict__ Ah,
    const f16* __restrict__ Bh, const f16* __restrict__ Bl,
    const float* __restrict__ bias,
    const f16* __restrict__ Up, f16* __restrict__ O,
    int resmode) {
  extern __shared__ char smem[];          // 128 KiB: A-ring 64KB | B-ring 64KB
  char* sAb = smem;
  char* sBb = smem + 65536;
  int t = threadIdx.x;

  // bijective XCD swizzle (m204)
  unsigned nwg = gridDim.x;
  unsigned bid = blockIdx.x;
  unsigned qq = nwg >> 3, rr8 = nwg & 7;
  unsigned xcd = bid & 7, idx8 = bid >> 3;
  unsigned swz = (xcd < rr8 ? xcd * (qq + 1) : rr8 * (qq + 1) + (xcd - rr8) * qq) + idx8;
  int bm = swz >> 3, bn = swz & 7;        // N blocks = 2048/256 = 8
  int rowA0 = bm * BM, rowB0 = bn * BN;

  int lane = t & 63, w = t >> 6;
  int wm = w >> 2, wn = w & 3;            // 2M x 4N wave grid
  int fr = lane & 15, kb = lane >> 4;

  f32x4 acc[8][4];
#pragma unroll
  for (int m = 0; m < 8; ++m)
#pragma unroll
    for (int n = 0; n < 4; ++n) acc[m][n] = (f32x4)0.f;

  int srow = t >> 2;                      // 0..127: staged row within 128-row group
  int sslot = t & 3;                      // 16B slot within 64B K-row

  auto stage = [&](int kt) {
    int buf = kt & 3;
    const f16* Bsrc = (kt < 64) ? Bh : Bl;
    int k0 = (kt & 63) * BK;              // same for A (repeated) and B (concat halves)
#pragma unroll
    for (int g = 0; g < 2; ++g) {
      int row = g * 128 + srow;
      int sl = sslot ^ ((row >> 1) & 3);  // inverse swizzle on the GLOBAL side
      const char* ga = (const char*)(Ah   + (size_t)(rowA0 + row) * DP1 + k0) + sl * 16;
      const char* gb = (const char*)(Bsrc + (size_t)(rowB0 + row) * DP1 + k0) + sl * 16;
      char* la = sAb + buf * 16384 + g * 8192 + w * 1024;   // wave-uniform base
      char* lb = sBb + buf * 16384 + g * 8192 + w * 1024;
      gload16(ga, la);
      gload16(gb, lb);
    }
  };

  // prologue: 2 K-tiles in flight; wait for kt=0 (4 newest = kt1's loads)
  stage(0);
  stage(1);
  asm volatile("s_waitcnt vmcnt(4)" ::: "memory");
  __builtin_amdgcn_s_barrier();

  for (int kt = 0; kt < KTILES; ++kt) {
    if (kt + 2 < KTILES) stage(kt + 2);
    const char* pa = sAb + (kt & 3) * 16384;
    const char* pb = sBb + (kt & 3) * 16384;
    f16x8 fb[4], fa[4];
#pragma unroll
    for (int n = 0; n < 4; ++n) {
      int row = wn * 64 + n * 16 + fr;
      fb[n] = *(const f16x8*)(pb + row * 64 + ((kb ^ ((row >> 1) & 3)) << 4));
    }
#pragma unroll
    for (int i = 0; i < 4; ++i) {
      int row = wm * 128 + i * 16 + fr;
      fa[i] = *(const f16x8*)(pa + row * 64 + ((kb ^ ((row >> 1) & 3)) << 4));
    }
    __builtin_amdgcn_s_setprio(1);
#pragma unroll
    for (int i = 0; i < 4; ++i)
#pragma unroll
      for (int n = 0; n < 4; ++n)
        acc[i][n] = __builtin_amdgcn_mfma_f32_16x16x32_f16(fa[i], fb[n], acc[i][n], 0, 0, 0);
    __builtin_amdgcn_s_setprio(0);
#pragma unroll
    for (int i = 0; i < 4; ++i) {
      int row = wm * 128 + (4 + i) * 16 + fr;
      fa[i] = *(const f16x8*)(pa + row * 64 + ((kb ^ ((row >> 1) & 3)) << 4));
    }
    __builtin_amdgcn_s_setprio(1);
#pragma unroll
    for (int i = 0; i < 4; ++i)
#pragma unroll
      for (int n = 0; n < 4; ++n)
        acc[4 + i][n] = __builtin_amdgcn_mfma_f32_16x16x32_f16(fa[i], fb[n], acc[4 + i][n], 0, 0, 0);
    __builtin_amdgcn_s_setprio(0);
    // boundary: kt+1's loads must have landed; kt+2's (4 newest) may stay in flight
    if (kt + 2 < KTILES) asm volatile("s_waitcnt vmcnt(4)" ::: "memory");
    else                 asm volatile("s_waitcnt vmcnt(0)" ::: "memory");
    __builtin_amdgcn_s_barrier();
  }

  const float H = 1.0f / 3.0f;
#pragma unroll
  for (int m = 0; m < 8; ++m) {
#pragma unroll
    for (int n = 0; n < 4; ++n) {
      int gcol = rowB0 + wn * 64 + n * 16 + fr;     // C/D: col = lane&15
      float bcol = bias[gcol];
#pragma unroll
      for (int j = 0; j < 4; ++j) {
        int grow = rowA0 + wm * 128 + m * 16 + (lane >> 4) * 4 + j;  // row=(lane>>4)*4+reg
        size_t off = (size_t)grow * MD + gcol;
        float v = acc[m][n][j] + bcol;
        float act = adtanh(v);
        float val = resmode ? ((float)Up[off] + H * act) : act;
        O[off] = (f16)val;
      }
    }
  }
}

// ---------------- final: out = u . ww + rowpart ----------------
__global__ void k_final(const f16* __restrict__ U,
                        const float* __restrict__ ww, const float* __restrict__ rowpart,
                        float* __restrict__ out, int row0, int nrows) {
  int wave = threadIdx.x >> 6, lane = threadIdx.x & 63;
  int rloc = blockIdx.x * 4 + wave;
  if (rloc >= nrows) return;
  int grow = row0 + rloc;
  const f16x8* ur = (const f16x8*)(U + (size_t)rloc * MD);
  float acc = 0.f;
#pragma unroll
  for (int q = 0; q < 4; ++q) {
    int idx = q * 64 + lane;              // f16x8 index (0..255)
    f16x8 uv = ur[idx];
    const f32x4* wp = (const f32x4*)(ww + (size_t)idx * 8);
    f32x4 w0 = wp[0], w1 = wp[1];
#pragma unroll
    for (int e = 0; e < 4; ++e) acc += (float)uv[e] * w0[e];
#pragma unroll
    for (int e = 0; e < 4; ++e) acc += (float)uv[4 + e] * w1[e];
  }
#pragma unroll
  for (int s = 32; s > 0; s >>= 1) acc += __shfl_xor(acc, s, 64);
  if (lane == 0) out[grow] = acc + rowpart[grow];
}

extern "C" void kernel_launch(void* const* d_in, const int* in_sizes, int n_in,
                              void* d_out, int out_size, void* d_ws, size_t ws_size,
                              hipStream_t stream) {
  const float* x  = (const float*)d_in[0];
  const float* A  = (const float*)d_in[1];
  const float* W0 = (const float*)d_in[2];
  const float* b0 = (const float*)d_in[3];
  const float* Wh = (const float*)d_in[4];
  const float* bh = (const float*)d_in[5];
  const float* ww = (const float*)d_in[6];
  const float* cw = (const float*)d_in[7];
  const float* cb = (const float*)d_in[8];
  float* out = (float*)d_out;

  char* ws = (char*)d_ws;
  f16* wsW = (f16*)ws;                                  // 4*2*NW f16 = 64 MiB
  size_t offRP = 4ull * 2 * NW * 2;                     // 67108864
  float* rowpart = (float*)(ws + offRP);                // 64 KiB
  size_t offSets = offRP + (size_t)NEX * 4;             // 67174400

  int chunkM = 16384;                                   // shrink if ws is small
  while (chunkM > 256 && offSets + 2ull * (size_t)chunkM * 4096 > ws_size) chunkM >>= 1;

  f16* s0 = (f16*)(ws + offSets);
  f16* s1 = (f16*)(ws + offSets + (size_t)chunkM * 4096);

  // allow 128 KiB dynamic LDS (idempotent; host-side, graph-capture-safe)
  hipFuncSetAttribute((const void*)k_gemm,
                      hipFuncAttributeMaxDynamicSharedMemorySize, 131072);

  k_split_w<<<2048, 256, 0, stream>>>(W0, Wh, wsW);

  for (int row0 = 0; row0 < NEX; row0 += chunkM) {
    int nrows = NEX - row0 < chunkM ? NEX - row0 : chunkM;
    int gblocks = (nrows / BM) * (MD / BN);
    int rblocks = (nrows + 3) / 4;
    k_rows<<<rblocks, 256, 0, stream>>>(x, A, cw, cb, rowpart, s0, row0, nrows);
    // layer 0: s0 -> s1 (no residual)
    k_gemm<<<gblocks, 512, 131072, stream>>>(s0, wsW + 0ull*NW, wsW + 1ull*NW, b0,
                                             nullptr, s1, 0);
    // layer 1: s1 -> s0 (residual from s1)
    k_gemm<<<gblocks, 512, 131072, stream>>>(s1, wsW + 2ull*NW, wsW + 3ull*NW, bh + 0*MD,
                                             s1, s0, 1);
    // layer 2: s0 -> s1
    k_gemm<<<gblocks, 512, 131072, stream>>>(s0, wsW + 4ull*NW, wsW + 5ull*NW, bh + 1*MD,
                                             s0, s1, 1);
    // layer 3: s1 -> s0
    k_gemm<<<gblocks, 512, 131072, stream>>>(s1, wsW + 6ull*NW, wsW + 7ull*NW, bh + 2*MD,
                                             s1, s0, 1);
    k_final<<<rblocks, 256, 0, stream>>>(s0, ww, rowpart, out, row0, nrows);
  }
}